// Round 1
// baseline (279.175 us; speedup 1.0000x reference)
//
#include <hip/hip_runtime.h>

// Sparse conv block: gather -> per-offset GEMM (bf16 MFMA) -> scatter-add ->
// BatchNorm (batch stats) -> ReLU.   MI355X / gfx950.

#define N_VOX   100000
#define C_INCH  64
#define C_OUTCH 64
#define K3      27
#define M_PAIRS 40000
#define BN_EPS  1e-5f

#define MPB 64                          // pairs per conv block
#define BLOCKS_PER_K (M_PAIRS / MPB)    // 625

typedef __attribute__((ext_vector_type(8))) short bf16x8;   // 8 bf16 in 4 VGPRs
typedef __attribute__((ext_vector_type(4))) float f32x4;    // MFMA C/D frag

__device__ __forceinline__ short f2bf(float f) {
  // round-to-nearest-even fp32 -> bf16 (inputs are finite; no NaN handling)
  unsigned u = __builtin_bit_cast(unsigned, f);
  u += 0x7FFFu + ((u >> 16) & 1u);
  return (short)(u >> 16);
}

// ---- W[k][i][c] (f32) -> Wt[k][c][i] (bf16) ---------------------------------
__global__ __launch_bounds__(256) void wconv_kernel(const float* __restrict__ W,
                                                    short* __restrict__ wt) {
  int id = blockIdx.x * 256 + threadIdx.x;
  if (id >= K3 * 4096) return;
  int k   = id >> 12;
  int rem = id & 4095;
  int c   = rem >> 6;
  int i   = rem & 63;
  wt[id] = f2bf(W[(k << 12) + (i << 6) + c]);   // wt[k*4096 + c*64 + i]
}

// ---- gather + GEMM + scatter-add -------------------------------------------
// Block: 256 threads = 4 waves, one kernel offset k, 64 rulebook pairs.
// Wave: 16 pairs x 64 channels via 8x mfma_f32_16x16x32_bf16.
// A frag lane l: row = pair (l&15), k-slots = (l>>4)*8 + j (+32 for s=1).
// B frag lane l: col = chan (l&15), same k-slot convention -> any HW k-perm cancels.
// C/D: col = lane&15, row = (lane>>4)*4 + reg   [m89-verified].
__global__ __launch_bounds__(256) void conv_kernel(const float* __restrict__ x,
                                                   const short* __restrict__ wt,
                                                   const int* __restrict__ in_idx,
                                                   const int* __restrict__ out_idx,
                                                   float* __restrict__ out) {
  __shared__ int s_in[MPB];
  __shared__ int s_out[MPB];
  int bx   = blockIdx.x;
  int k    = bx / BLOCKS_PER_K;
  int base = (bx % BLOCKS_PER_K) * MPB;
  int t    = threadIdx.x;
  if (t < MPB)            s_in[t]        = in_idx[k * M_PAIRS + base + t];
  else if (t < 2 * MPB)   s_out[t - MPB] = out_idx[k * M_PAIRS + base + (t - MPB)];
  __syncthreads();

  int wave = t >> 6, lane = t & 63;
  int g    = lane >> 4;           // k-slot group
  int c0   = lane & 15;

  // ---- A fragments: gather one x row per (wave,lane&15), convert to bf16
  int prow = (wave << 4) + c0;    // pair index within block (A-row role)
  const float* xrow = x + (long)s_in[prow] * C_INCH + g * 8;
  float4 a0lo = *(const float4*)(xrow);
  float4 a0hi = *(const float4*)(xrow + 4);
  float4 a1lo = *(const float4*)(xrow + 32);
  float4 a1hi = *(const float4*)(xrow + 36);
  bf16x8 a0, a1;
  a0[0] = f2bf(a0lo.x); a0[1] = f2bf(a0lo.y); a0[2] = f2bf(a0lo.z); a0[3] = f2bf(a0lo.w);
  a0[4] = f2bf(a0hi.x); a0[5] = f2bf(a0hi.y); a0[6] = f2bf(a0hi.z); a0[7] = f2bf(a0hi.w);
  a1[0] = f2bf(a1lo.x); a1[1] = f2bf(a1lo.y); a1[2] = f2bf(a1lo.z); a1[3] = f2bf(a1lo.w);
  a1[4] = f2bf(a1hi.x); a1[5] = f2bf(a1hi.y); a1[6] = f2bf(a1hi.z); a1[7] = f2bf(a1hi.w);

  // ---- B fragments from Wt[k][c][i] (contiguous 16B per lane, L1-resident)
  const short* wtk = wt + k * 4096;
  f32x4 acc[4];
  #pragma unroll
  for (int n = 0; n < 4; ++n) { acc[n][0] = 0.f; acc[n][1] = 0.f; acc[n][2] = 0.f; acc[n][3] = 0.f; }
  #pragma unroll
  for (int n = 0; n < 4; ++n) {
    int c = n * 16 + c0;
    bf16x8 b0 = *(const bf16x8*)(wtk + c * 64 + g * 8);
    bf16x8 b1 = *(const bf16x8*)(wtk + c * 64 + 32 + g * 8);
    acc[n] = __builtin_amdgcn_mfma_f32_16x16x32_bf16(a0, b0, acc[n], 0, 0, 0);
    acc[n] = __builtin_amdgcn_mfma_f32_16x16x32_bf16(a1, b1, acc[n], 0, 0, 0);
  }

  // ---- scatter-add: lane holds rows (lane>>4)*4+j, chans n*16+c0
  int rbase = (wave << 4) + ((lane >> 4) << 2);
  #pragma unroll
  for (int j = 0; j < 4; ++j) {
    long o = (long)s_out[rbase + j] * C_OUTCH;
    #pragma unroll
    for (int n = 0; n < 4; ++n) {
      unsafeAtomicAdd(&out[o + n * 16 + c0], acc[n][j]);
    }
  }
}

// ---- per-channel sum / sum-of-squares --------------------------------------
__global__ __launch_bounds__(256) void stats_kernel(const float* __restrict__ out,
                                                    float* __restrict__ stats) {
  __shared__ float s1[256], s2[256];
  int t = threadIdx.x;
  int c = t & 63;
  int rsub = t >> 6;
  float sum1 = 0.f, sum2 = 0.f;
  for (int r = blockIdx.x * 4 + rsub; r < N_VOX; r += gridDim.x * 4) {
    float v = out[r * 64 + c];
    sum1 += v;
    sum2 += v * v;
  }
  s1[t] = sum1; s2[t] = sum2;
  __syncthreads();
  if (t < 64) {
    sum1 = s1[t] + s1[t + 64] + s1[t + 128] + s1[t + 192];
    sum2 = s2[t] + s2[t + 64] + s2[t + 128] + s2[t + 192];
    unsafeAtomicAdd(&stats[c], sum1);
    unsafeAtomicAdd(&stats[64 + c], sum2);
  }
}

// ---- finalize BN + ReLU in place -------------------------------------------
__global__ __launch_bounds__(256) void norm_kernel(float* __restrict__ out,
                                                   const float* __restrict__ stats,
                                                   const float* __restrict__ gamma,
                                                   const float* __restrict__ beta) {
  int i4 = blockIdx.x * 256 + threadIdx.x;          // one float4 per thread
  if (i4 >= N_VOX * (C_OUTCH / 4)) return;
  const float invN = 1.0f / (float)N_VOX;
  float4 v = ((const float4*)out)[i4];
  int c0 = (i4 << 2) & 63;
  float r[4] = {v.x, v.y, v.z, v.w};
  #pragma unroll
  for (int j = 0; j < 4; ++j) {
    int c = c0 + j;
    float mean = stats[c] * invN;
    float ex2  = stats[64 + c] * invN;
    float var  = ex2 - mean * mean;
    float scale = gamma[c] * rsqrtf(var + BN_EPS);
    float shift = beta[c] - mean * scale;
    r[j] = fmaxf(r[j] * scale + shift, 0.0f);
  }
  v.x = r[0]; v.y = r[1]; v.z = r[2]; v.w = r[3];
  ((float4*)out)[i4] = v;
}

extern "C" void kernel_launch(void* const* d_in, const int* in_sizes, int n_in,
                              void* d_out, int out_size, void* d_ws, size_t ws_size,
                              hipStream_t stream) {
  const float* x      = (const float*)d_in[0];
  const float* W      = (const float*)d_in[1];
  const float* gamma  = (const float*)d_in[2];
  const float* beta   = (const float*)d_in[3];
  const int*   in_idx = (const int*)d_in[4];
  const int*   out_idx= (const int*)d_in[5];
  float* out = (float*)d_out;

  // ws layout: [0, 221184) Wt bf16 (27*64*64 shorts), [221184, 221696) stats
  short* wt    = (short*)d_ws;
  float* stats = (float*)((char*)d_ws + (size_t)(K3 * 4096 * 2));

  hipMemsetAsync(d_out, 0, (size_t)N_VOX * C_OUTCH * sizeof(float), stream);
  hipMemsetAsync(stats, 0, 2 * C_OUTCH * sizeof(float), stream);

  wconv_kernel<<<(K3 * 4096 + 255) / 256, 256, 0, stream>>>(W, wt);
  conv_kernel<<<K3 * BLOCKS_PER_K, 256, 0, stream>>>(x, wt, in_idx, out_idx, out);
  stats_kernel<<<256, 256, 0, stream>>>(out, stats);
  norm_kernel<<<(N_VOX * (C_OUTCH / 4) + 255) / 256, 256, 0, stream>>>(out, stats, gamma, beta);
}